// Round 6
// baseline (254.862 us; speedup 1.0000x reference)
//
#include <hip/hip_runtime.h>
#include <hip/hip_cooperative_groups.h>

// hinge one-vs-rest loss:
//   loss = (1/B) * sum_{all elements} max(1 - o*sign(l), 0),  B = 16384
// R5 post-mortem: three MLP attempts all null (VGPR never rose, time flat)
// -> kernel was never MLP-limited; 32 waves/CU give ample TLP. Split:
// stage1 ~24us (131MB @ ~5.5 TB/s, 87% of achievable) + ~4us launch/stage2
// overhead. This round removes the overhead: single cooperative kernel,
// grid.sync(), block 0 finishes. Stage1 load structure unchanged.

namespace cg = cooperative_groups;

constexpr int BLOCK  = 256;
constexpr int UNROLL = 8;               // float4 per thread per array
constexpr int TILE   = BLOCK * UNROLL;  // 2048 float4 per block

__device__ __forceinline__ float block_reduce(float acc, float* wave_sums) {
    #pragma unroll
    for (int off = 32; off > 0; off >>= 1)
        acc += __shfl_down(acc, off, 64);
    const int lane = threadIdx.x & 63;
    const int wid  = threadIdx.x >> 6;
    if (lane == 0) wave_sums[wid] = acc;
    __syncthreads();
    float s = 0.0f;
    #pragma unroll
    for (int w = 0; w < BLOCK / 64; ++w) s += wave_sums[w];
    return s;
}

__device__ __forceinline__ float hinge_partial_exact(
    const float4* __restrict__ out4, const float4* __restrict__ lab4)
{
    const int tid = threadIdx.x;
    const size_t base = (size_t)blockIdx.x * TILE + tid;
    const float4* __restrict__ po = out4 + base;
    const float4* __restrict__ pl = lab4 + base;

    float4 o[UNROLL], l[UNROLL];
    #pragma unroll
    for (int u = 0; u < UNROLL; ++u) o[u] = po[u * BLOCK];
    #pragma unroll
    for (int u = 0; u < UNROLL; ++u) l[u] = pl[u * BLOCK];

    float a0 = 0.f, a1 = 0.f, a2 = 0.f, a3 = 0.f;
    #pragma unroll
    for (int u = 0; u < UNROLL; ++u) {
        a0 += fmaxf(1.0f - (l[u].x >= 0.0f ? o[u].x : -o[u].x), 0.0f);
        a1 += fmaxf(1.0f - (l[u].y >= 0.0f ? o[u].y : -o[u].y), 0.0f);
        a2 += fmaxf(1.0f - (l[u].z >= 0.0f ? o[u].z : -o[u].z), 0.0f);
        a3 += fmaxf(1.0f - (l[u].w >= 0.0f ? o[u].w : -o[u].w), 0.0f);
    }
    return (a0 + a1) + (a2 + a3);
}

// Fused cooperative kernel: partials -> grid.sync() -> block 0 finishes.
__global__ __launch_bounds__(BLOCK) void hinge_fused_coop(
    const float4* __restrict__ out4,
    const float4* __restrict__ lab4,
    float* __restrict__ partials,
    float* __restrict__ loss,
    float inv_b)
{
    __shared__ float wave_sums[BLOCK / 64];
    const float acc = hinge_partial_exact(out4, lab4);
    const float s = block_reduce(acc, wave_sums);
    if (threadIdx.x == 0) partials[blockIdx.x] = s;

    cg::this_grid().sync();   // all partials globally visible after this

    if (blockIdx.x == 0) {
        float a = 0.0f;
        for (int i = threadIdx.x; i < (int)gridDim.x; i += BLOCK)
            a += partials[i];
        __syncthreads();  // wave_sums reuse: ensure phase-1 reads done
        const float t = block_reduce(a, wave_sums);
        if (threadIdx.x == 0) loss[0] = t * inv_b;
    }
}

// ---- Fallback (non-exact tiling or cooperative launch failure): two-stage ----
__global__ __launch_bounds__(BLOCK) void hinge_stage1_guarded(
    const float4* __restrict__ out4,
    const float4* __restrict__ lab4,
    float* __restrict__ partials,
    int n4)
{
    const int tid = threadIdx.x;
    const long long base = (long long)blockIdx.x * TILE + tid;
    float acc = 0.0f;
    #pragma unroll
    for (int u = 0; u < UNROLL; ++u) {
        const long long idx = base + (long long)u * BLOCK;
        if (idx < n4) {
            const float4 o = out4[idx];
            const float4 l = lab4[idx];
            acc += fmaxf(1.0f - (l.x >= 0.0f ? o.x : -o.x), 0.0f);
            acc += fmaxf(1.0f - (l.y >= 0.0f ? o.y : -o.y), 0.0f);
            acc += fmaxf(1.0f - (l.z >= 0.0f ? o.z : -o.z), 0.0f);
            acc += fmaxf(1.0f - (l.w >= 0.0f ? o.w : -o.w), 0.0f);
        }
    }
    __shared__ float wave_sums[BLOCK / 64];
    const float s = block_reduce(acc, wave_sums);
    if (tid == 0) partials[blockIdx.x] = s;
}

__global__ __launch_bounds__(BLOCK) void hinge_stage2_kernel(
    const float* __restrict__ partials,
    float* __restrict__ loss,
    int n_partials, float inv_b)
{
    float acc = 0.0f;
    for (int i = threadIdx.x; i < n_partials; i += BLOCK)
        acc += partials[i];
    __shared__ float wave_sums[BLOCK / 64];
    const float s = block_reduce(acc, wave_sums);
    if (threadIdx.x == 0) loss[0] = s * inv_b;
}

extern "C" void kernel_launch(void* const* d_in, const int* in_sizes, int n_in,
                              void* d_out, int out_size, void* d_ws, size_t ws_size,
                              hipStream_t stream) {
    const float* outputs = (const float*)d_in[0];
    const float* labels  = (const float*)d_in[1];
    float* loss     = (float*)d_out;
    float* partials = (float*)d_ws;   // grid floats, written before read

    const long long n = (long long)in_sizes[0];   // 16,384,000
    const int n4 = (int)(n / 4);                  // 4,096,000
    const float inv_b = 1.0f / 16384.0f;

    const int grid = (n4 + TILE - 1) / TILE;      // 2000 blocks

    if (n4 % TILE == 0 && grid <= 2048) {
        const float4* o4 = (const float4*)outputs;
        const float4* l4 = (const float4*)labels;
        void* args[] = { (void*)&o4, (void*)&l4, (void*)&partials,
                         (void*)&loss, (void*)&inv_b };
        hipError_t err = hipLaunchCooperativeKernel(
            (const void*)hinge_fused_coop, dim3(grid), dim3(BLOCK),
            args, 0, stream);
        if (err == hipSuccess) return;
        // fall through to two-stage on failure
    }
    hinge_stage1_guarded<<<grid, BLOCK, 0, stream>>>(
        (const float4*)outputs, (const float4*)labels, partials, n4);
    hinge_stage2_kernel<<<1, BLOCK, 0, stream>>>(partials, loss, grid, inv_b);
}

// Round 7
// 39.448 us; speedup vs baseline: 6.4607x; 6.4607x over previous
//
#include <hip/hip_runtime.h>

// hinge one-vs-rest loss:
//   loss = (1/B) * sum_{all elements} max(1 - o*sign(l), 0),  B = 16384
// R6 post-mortem: cooperative grid.sync() = 254us (grid-wide software barrier
// across 8 XCDs). Reverted. This round: single kernel, last-block-finish via
// ONE int ticket atomic per block. R1/R2 calibration: same-address atomics
// serve ~1/25ns; 500 blocks over ~24us (48ns spacing) -> no queueing.
// 500 blocks x 512 threads x 16 float4 = 4,096,000 float4 exactly.

constexpr int BLOCK  = 512;
constexpr int UNROLL = 16;              // float4 per thread per array
constexpr int TILE   = BLOCK * UNROLL;  // 8192 float4 per block
constexpr int NWAVES = BLOCK / 64;

__device__ __forceinline__ float block_reduce(float acc, float* wave_sums) {
    #pragma unroll
    for (int off = 32; off > 0; off >>= 1)
        acc += __shfl_down(acc, off, 64);
    const int lane = threadIdx.x & 63;
    const int wid  = threadIdx.x >> 6;
    if (lane == 0) wave_sums[wid] = acc;
    __syncthreads();
    float s = 0.0f;
    #pragma unroll
    for (int w = 0; w < NWAVES; ++w) s += wave_sums[w];
    return s;
}

// Single fused kernel: partial -> ticket -> last block finishes.
__global__ __launch_bounds__(BLOCK) void hinge_fused_ticket(
    const float4* __restrict__ out4,
    const float4* __restrict__ lab4,
    float* __restrict__ partials,
    unsigned* __restrict__ ticket,
    float* __restrict__ loss,
    int grid_n, float inv_b)
{
    const int tid = threadIdx.x;
    const size_t base = (size_t)blockIdx.x * TILE + tid;
    const float4* __restrict__ po = out4 + base;
    const float4* __restrict__ pl = lab4 + base;

    float a0 = 0.f, a1 = 0.f, a2 = 0.f, a3 = 0.f;
    #pragma unroll
    for (int u = 0; u < UNROLL; ++u) {
        const float4 o = po[u * BLOCK];
        const float4 l = pl[u * BLOCK];
        a0 += fmaxf(1.0f - (l.x >= 0.0f ? o.x : -o.x), 0.0f);
        a1 += fmaxf(1.0f - (l.y >= 0.0f ? o.y : -o.y), 0.0f);
        a2 += fmaxf(1.0f - (l.z >= 0.0f ? o.z : -o.z), 0.0f);
        a3 += fmaxf(1.0f - (l.w >= 0.0f ? o.w : -o.w), 0.0f);
    }
    float acc = (a0 + a1) + (a2 + a3);

    __shared__ float wave_sums[NWAVES];
    __shared__ unsigned is_last;
    const float s = block_reduce(acc, wave_sums);

    if (tid == 0) {
        partials[blockIdx.x] = s;
        __threadfence();                       // release partial before ticket
        const unsigned t = atomicAdd(ticket, 1u);
        // mod-grid test: correct even on first call when *ticket is 0xAAAAAAAA
        // poison; exactly one of any grid_n consecutive tickets matches.
        is_last = ((t % (unsigned)grid_n) == (unsigned)(grid_n - 1)) ? 1u : 0u;
    }
    __syncthreads();

    if (is_last) {
        __threadfence();                       // acquire all partials
        float a = (tid < grid_n) ? partials[tid] : 0.0f;
        __syncthreads();                       // wave_sums reuse barrier
        const float t2 = block_reduce(a, wave_sums);
        if (tid == 0) {
            loss[0] = t2 * inv_b;
            atomicExch(ticket, 0u);            // clean state for next replay
        }
    }
}

// ---- Fallback for non-exact sizes: guarded two-stage ----
__global__ __launch_bounds__(256) void hinge_stage1_guarded(
    const float4* __restrict__ out4,
    const float4* __restrict__ lab4,
    float* __restrict__ partials,
    int n4)
{
    const int tid = threadIdx.x;
    const long long base = (long long)blockIdx.x * (256LL * 8) + tid;
    float acc = 0.0f;
    #pragma unroll
    for (int u = 0; u < 8; ++u) {
        const long long idx = base + (long long)u * 256;
        if (idx < n4) {
            const float4 o = out4[idx];
            const float4 l = lab4[idx];
            acc += fmaxf(1.0f - (l.x >= 0.0f ? o.x : -o.x), 0.0f);
            acc += fmaxf(1.0f - (l.y >= 0.0f ? o.y : -o.y), 0.0f);
            acc += fmaxf(1.0f - (l.z >= 0.0f ? o.z : -o.z), 0.0f);
            acc += fmaxf(1.0f - (l.w >= 0.0f ? o.w : -o.w), 0.0f);
        }
    }
    #pragma unroll
    for (int off = 32; off > 0; off >>= 1)
        acc += __shfl_down(acc, off, 64);
    __shared__ float ws[4];
    if ((tid & 63) == 0) ws[tid >> 6] = acc;
    __syncthreads();
    if (tid == 0) partials[blockIdx.x] = ws[0] + ws[1] + ws[2] + ws[3];
}

__global__ __launch_bounds__(256) void hinge_stage2_kernel(
    const float* __restrict__ partials,
    float* __restrict__ loss,
    int n_partials, float inv_b)
{
    float acc = 0.0f;
    for (int i = threadIdx.x; i < n_partials; i += 256)
        acc += partials[i];
    #pragma unroll
    for (int off = 32; off > 0; off >>= 1)
        acc += __shfl_down(acc, off, 64);
    __shared__ float ws[4];
    if ((threadIdx.x & 63) == 0) ws[threadIdx.x >> 6] = acc;
    __syncthreads();
    if (threadIdx.x == 0) loss[0] = (ws[0] + ws[1] + ws[2] + ws[3]) * inv_b;
}

extern "C" void kernel_launch(void* const* d_in, const int* in_sizes, int n_in,
                              void* d_out, int out_size, void* d_ws, size_t ws_size,
                              hipStream_t stream) {
    const float* outputs = (const float*)d_in[0];
    const float* labels  = (const float*)d_in[1];
    float* loss = (float*)d_out;

    // d_ws layout: [0] ticket counter (4B), [256B..] partials (grid floats).
    unsigned* ticket  = (unsigned*)d_ws;
    float* partials   = (float*)((char*)d_ws + 256);

    const long long n = (long long)in_sizes[0];   // 16,384,000
    const int n4 = (int)(n / 4);                  // 4,096,000
    const float inv_b = 1.0f / 16384.0f;

    if (n4 % TILE == 0) {
        const int grid = n4 / TILE;               // 500 blocks
        hinge_fused_ticket<<<grid, BLOCK, 0, stream>>>(
            (const float4*)outputs, (const float4*)labels,
            partials, ticket, loss, grid, inv_b);
    } else {
        const int grid = (n4 + 256 * 8 - 1) / (256 * 8);
        hinge_stage1_guarded<<<grid, 256, 0, stream>>>(
            (const float4*)outputs, (const float4*)labels, partials, n4);
        hinge_stage2_kernel<<<1, 256, 0, stream>>>(partials, loss, grid, inv_b);
    }
}